// Round 7
// baseline (163.222 us; speedup 1.0000x reference)
//
#include <hip/hip_runtime.h>

#define T_DIM 64
#define NP 4096                      /* N*C pairs; one block per p */
#define D_OUTC 129
#define ROW_STRIDE (NP * D_OUTC)     /* 528384 floats between t-slices */

// out[t,n,c,d] = w * sum_ch v_ch[t],  v_ch = LIF(x_ch[(t - s_ch(d)) % 64])
// Direct per-thread dual recurrence: lane owns d, keeps v0,v1 in registers.
// x duplicated in LDS (x[t]==x[t+64]) so the circular shift is a fixed base offset.
__global__ __launch_bounds__(128, 8) void jeffress_kernel(
    const float* __restrict__ input,        // (T, N, C, 2)
    const float* __restrict__ delay_param,  // (129, 1)
    const float* __restrict__ weight,       // scalar
    const float* __restrict__ u,            // (N, C, 129, 2)
    float* __restrict__ out)                // (T, N, C, 129)
{
    __shared__ float x_lds[2][128];        // duplicated time series per channel
    __shared__ int caps[2];                // 63 - argmax_t

    // XCD swizzle: adjacent p share an XCD so 516B row-boundary lines merge in L2.
    const int p    = ((blockIdx.x & 7) << 9) | (blockIdx.x >> 3);
    const int tid  = threadIdx.x;
    const int lane = tid & 63, wave = tid >> 6;
    const float DECAY = 0.6065306597126334f;  // exp(-1/2), same f32 as reference

    // ---- phase 1: load x (wave=ch, lane=t), duplicate, butterfly argmax ----
    {
        float xv = input[(lane * NP + p) * 2 + wave];
        x_lds[wave][lane]      = xv;
        x_lds[wave][lane + 64] = xv;
        unsigned b = __float_as_uint(xv);
        b ^= (b & 0x80000000u) ? 0xffffffffu : 0x80000000u;  // total float order
        unsigned long long key = ((unsigned long long)b << 32) | (unsigned)(63 - lane);
        #pragma unroll
        for (int mm = 1; mm < 64; mm <<= 1) {
            unsigned long long o = __shfl_xor(key, mm, 64);
            if (o > key) key = o;              // ties -> larger (63-t) -> first t
        }
        if (lane == 0) caps[wave] = (int)(key & 0xffffffffull);
    }
    __syncthreads();

    const float w   = weight[0];
    const float c0f = (float)caps[0], c1f = (float)caps[1];

    const int d     = (wave << 6) | lane;      // 0..127; tid 127 also owns d=128
    const bool dual = (tid == 127);

    // per-d shifts: stochastic rounding (generic) + clamp, per reference
    auto calc = [&](int dd, int& s0, int& s1) {
        float dp = delay_param[dd];
        float b0 = fmaxf(dp, 0.0f), b1 = fmaxf(-dp, 0.0f);  // relu(cat([dp,-dp]))
        float2 uu = ((const float2*)u)[p * D_OUTC + dd];
        float f0 = floorf(b0), f1 = floorf(b1);
        float r0 = (uu.x < b0 - f0) ? f0 + 1.0f : f0;
        float r1 = (uu.y < b1 - f1) ? f1 + 1.0f : f1;
        s0 = (int)fminf(r0, c0f);
        s1 = (int)fminf(r1, c1f);
    };

    int s0, s1;
    calc(d, s0, s1);
    int e0 = 0, e1 = 0;
    if (dual) calc(128, e0, e1);

    // x_ch[64 - s + t] == x_ch[(t - s) mod 64]; index stays in [1,127]
    const float* x0 = &x_lds[0][64 - s0];
    const float* x1 = &x_lds[1][64 - s1];
    const float* y0 = &x_lds[0][64 - e0];
    const float* y1 = &x_lds[1][64 - e1];

    float v0 = 0.0f, v1 = 0.0f, ve0 = 0.0f, ve1 = 0.0f;
    float* rp = out + (size_t)p * D_OUTC + d;

    #pragma unroll 4
    for (int t = 0; t < T_DIM; ++t) {
        v0 = v0 * DECAY + x0[t];               // consecutive addrs across lanes: free
        v1 = v1 * DECAY + x1[t];               // broadcast (s1 uniform 0) or 2-way
        rp[0] = w * (v0 + v1);                 // 256B wave burst, via L2
        if (dual) {                            // d=128 piggybacks on tid 127
            ve0 = ve0 * DECAY + y0[t];
            ve1 = ve1 * DECAY + y1[t];
            rp[1] = w * (ve0 + ve1);
        }
        rp += ROW_STRIDE;
    }
}

extern "C" void kernel_launch(void* const* d_in, const int* in_sizes, int n_in,
                              void* d_out, int out_size, void* d_ws, size_t ws_size,
                              hipStream_t stream) {
    const float* input       = (const float*)d_in[0]; // (64,16,256,2)
    const float* delay_param = (const float*)d_in[1]; // (129,1)
    const float* weight      = (const float*)d_in[2]; // scalar
    const float* u           = (const float*)d_in[3]; // (16,256,129,2)
    float* out = (float*)d_out;                       // (64,16,256,129)

    jeffress_kernel<<<NP, 128, 0, stream>>>(input, delay_param, weight, u, out);
}

// Round 8
// 162.733 us; speedup vs baseline: 1.0030x; 1.0030x over previous
//
#include <hip/hip_runtime.h>

#define T_DIM 64
#define NP 4096                      /* N*C pairs; one block per p */
#define D_OUTC 129
#define ROW_STRIDE (NP * D_OUTC)     /* floats between t-slices */

// Closed form: with z=[x;x], H[i] = sum_{j<=i} decay^{i-j} z[j]  (i in 0..127),
// the shifted+LIF-filtered series is  y_s[t] = H[64-s+t] - decay^{t+1} * H[63-s].
// out[t,p,d] = w*(y_{s0(d)}^{ch0}[t] + y_{s1(d)}^{ch1}[t]); fold w into H.
// Per element: 2 LDS reads + FMA. No G-table, no recurrence, no main-loop barrier.
__global__ __launch_bounds__(128, 8) void jeffress_kernel(
    const float* __restrict__ input,        // (T, N, C, 2)
    const float* __restrict__ delay_param,  // (129, 1)
    const float* __restrict__ weight,       // scalar
    const float* __restrict__ u,            // (N, C, 129, 2)
    float* __restrict__ out)                // (T, N, C, 129)
{
    __shared__ float Hw0[128], Hw1[128];   // w * H per channel
    __shared__ int caps[2];                // 63 - argmax_t

    // XCD swizzle: adjacent p share an XCD so 516B row-boundary lines merge in L2.
    const int p    = ((blockIdx.x & 7) << 9) | (blockIdx.x >> 3);
    const int tid  = threadIdx.x;
    const int lane = tid & 63, wv = tid >> 6;
    const float DECAY = 0.6065306597126334f;   // exp(-1/2), f32-rounded as reference

    // both channels for time t=lane (adjacent floats -> one float2 load)
    float2 xp = ((const float2*)input)[lane * NP + p];

    // ---- butterfly argmax, wave w handles channel w (first-occurrence ties) ----
    {
        float xv = wv ? xp.y : xp.x;
        unsigned b = __float_as_uint(xv);
        b ^= (b & 0x80000000u) ? 0xffffffffu : 0x80000000u;  // total float order
        unsigned long long key = ((unsigned long long)b << 32) | (unsigned)(63 - lane);
        #pragma unroll
        for (int mm = 1; mm < 64; mm <<= 1) {
            unsigned long long o = __shfl_xor(key, mm, 64);
            if (o > key) key = o;
        }
        if (lane == 0) caps[wv] = (int)(key & 0xffffffffull);
    }

    // ---- wave 0: dual-channel Kogge-Stone scan -> H[0..63], scaled by w ----
    const float w = weight[0];
    if (wv == 0) {
        float v0 = xp.x, v1 = xp.y;
        const float dks[6] = {0.6065306597126334f,  // decay^1
                              0.36787944117144233f, // decay^2
                              0.1353352832366127f,  // decay^4
                              0.01831563888873418f, // decay^8
                              3.3546262790251185e-4f,  // decay^16
                              1.1253517471925912e-7f}; // decay^32
        #pragma unroll
        for (int k = 0; k < 6; ++k) {
            int o = 1 << k;
            float p0 = __shfl_up(v0, o, 64);
            float p1 = __shfl_up(v1, o, 64);
            if (lane >= o) { v0 += dks[k] * p0; v1 += dks[k] * p1; }
        }
        Hw0[lane] = w * v0;
        Hw1[lane] = w * v1;
    }
    __syncthreads();
    // ---- wave 1: upper half  H[64+k] = H[k] + decay^{k+1} * H[63] ----
    if (wv == 1) {
        float f = exp2f(-0.7213475204444817f * (float)(lane + 1)); // decay^{k+1}
        Hw0[64 + lane] = Hw0[lane] + f * Hw0[63];
        Hw1[64 + lane] = Hw1[lane] + f * Hw1[63];
    }
    __syncthreads();

    const float c0f = (float)caps[0], c1f = (float)caps[1];

    // per-d shifts: stochastic rounding (generic) + clamp, per reference
    auto calc = [&](int dd, int& s0, int& s1) {
        float dp = delay_param[dd];
        float b0 = fmaxf(dp, 0.0f), b1 = fmaxf(-dp, 0.0f);  // relu(cat([dp,-dp]))
        float2 uu = ((const float2*)u)[p * D_OUTC + dd];
        float f0 = floorf(b0), f1 = floorf(b1);
        float r0 = (uu.x < b0 - f0) ? f0 + 1.0f : f0;
        float r1 = (uu.y < b1 - f1) ? f1 + 1.0f : f1;
        s0 = (int)fminf(r0, c0f);
        s1 = (int)fminf(r1, c1f);
    };

    int s0, s1; calc(tid, s0, s1);
    const float* pA0 = &Hw0[64 - s0];       // gather bases; index +t stays in [1,127]
    const float* pA1 = &Hw1[64 - s1];
    const float Cw = pA0[-1] + pA1[-1];     // w*(H0[63-s0] + H1[63-s1])

    const bool dual = (tid == 127);         // tid 127 also owns d=128
    int e0 = 0, e1 = 0; if (dual) calc(128, e0, e1);
    const float* pB0 = &Hw0[64 - e0];
    const float* pB1 = &Hw1[64 - e1];
    const float CwE = dual ? (pB0[-1] + pB1[-1]) : 0.0f;

    float* rp = out + (size_t)p * D_OUTC + tid;
    float Dg = DECAY;                       // decay^{t+1} at group start
    const float K[8] = {1.0f, 0.6065306597126334f, 0.36787944117144233f,
                        0.22313016014842982f, 0.1353352832366127f,
                        0.0820849986238988f, 0.049787068367863944f,
                        0.030197383422318501f};  // decay^j, j=0..7

    for (int tg = 0; tg < T_DIM; tg += 8) {
        float CwD  = Cw  * Dg;
        float CwDE = CwE * Dg;
        #pragma unroll
        for (int j = 0; j < 8; ++j) {
            // addresses are base + immediate: compiler prefetches the whole group
            float val = pA0[tg + j] + pA1[tg + j] - K[j] * CwD;
            rp[0] = val;
            if (dual) {
                float ve = pB0[tg + j] + pB1[tg + j] - K[j] * CwDE;
                rp[1] = ve;
            }
            rp += ROW_STRIDE;
        }
        Dg *= 0.01831563888873418f;         // decay^8
    }
}

extern "C" void kernel_launch(void* const* d_in, const int* in_sizes, int n_in,
                              void* d_out, int out_size, void* d_ws, size_t ws_size,
                              hipStream_t stream) {
    const float* input       = (const float*)d_in[0]; // (64,16,256,2)
    const float* delay_param = (const float*)d_in[1]; // (129,1)
    const float* weight      = (const float*)d_in[2]; // scalar
    const float* u           = (const float*)d_in[3]; // (16,256,129,2)
    float* out = (float*)d_out;                       // (64,16,256,129)

    jeffress_kernel<<<NP, 128, 0, stream>>>(input, delay_param, weight, u, out);
}

// Round 9
// 157.072 us; speedup vs baseline: 1.0392x; 1.0360x over previous
//
#include <hip/hip_runtime.h>

#define T_DIM 64
#define NP 4096                      /* total (n,c) pairs */
#define D_OUTC 129
#define ROW_STRIDE (NP * D_OUTC)     /* floats between t-slices */
#define PPB 4                        /* adjacent p's per block -> 2064B contiguous span per t */

typedef float v2f __attribute__((ext_vector_type(2)));

// Closed form: with z=[x;x], H[i] = sum_{j<=i} decay^{i-j} z[j] (i in 0..127),
// shifted+filtered series y_s[t] = H[64-s+t] - decay^{t+1} * H[63-s].
// out[t,p,d] = w*(y_{s0}^{ch0}[t] + y_{s1}^{ch1}[t]); w folded into H.
// Block = 4 adjacent p: per t writes one contiguous 16B-aligned 2064B span
// (full 64B lines except 2 boundary partials merged with same-XCD neighbors).
__global__ __launch_bounds__(256, 4) void jeffress_kernel(
    const float* __restrict__ input,        // (T, N, C, 2)
    const float* __restrict__ delay_param,  // (129, 1)
    const float* __restrict__ weight,       // scalar
    const float* __restrict__ u,            // (N, C, 129, 2)
    float* __restrict__ out)                // (T, N, C, 129)
{
    __shared__ float Hw[PPB * 2 * 128];    // [p_local][ch][i], w-scaled
    __shared__ int caps[PPB][2];           // 63 - argmax_t

    const int blk = blockIdx.x;
    // XCD swizzle: adjacent groups share an XCD so boundary lines merge in its L2
    const int g   = ((blk & 7) << 7) | (blk >> 3);   // [0,1024)
    const int p0  = g * PPB;
    const int tid = threadIdx.x;
    const int lane = tid & 63, wv = tid >> 6;        // wave wv owns p_local = wv
    const float DECAY = 0.6065306597126334f;         // exp(-1/2), f32 as reference
    const float w = weight[0];

    // ---- setup: per-wave load, argmax, dual-channel weighted Kogge-Stone scan ----
    {
        float2 xp = ((const float2*)input)[lane * NP + p0 + wv];
        #pragma unroll
        for (int ch = 0; ch < 2; ++ch) {             // first-occurrence argmax
            float xv = ch ? xp.y : xp.x;
            unsigned b = __float_as_uint(xv);
            b ^= (b & 0x80000000u) ? 0xffffffffu : 0x80000000u;  // total float order
            unsigned long long key = ((unsigned long long)b << 32) | (unsigned)(63 - lane);
            #pragma unroll
            for (int mm = 1; mm < 64; mm <<= 1) {
                unsigned long long o = __shfl_xor(key, mm, 64);
                if (o > key) key = o;                // ties -> larger (63-t) -> first t
            }
            if (lane == 0) caps[wv][ch] = (int)(key & 0xffffffffull);
        }
        float v0 = xp.x, v1 = xp.y;
        const float dks[6] = {0.6065306597126334f,     // decay^1
                              0.36787944117144233f,    // decay^2
                              0.1353352832366127f,     // decay^4
                              0.01831563888873418f,    // decay^8
                              3.3546262790251185e-4f,  // decay^16
                              1.1253517471925912e-7f}; // decay^32
        #pragma unroll
        for (int k = 0; k < 6; ++k) {
            int o = 1 << k;
            float q0 = __shfl_up(v0, o, 64);
            float q1 = __shfl_up(v1, o, 64);
            if (lane >= o) { v0 += dks[k] * q0; v1 += dks[k] * q1; }
        }
        float h063 = __shfl(v0, 63, 64);
        float h163 = __shfl(v1, 63, 64);
        float f = exp2f(-0.7213475204444817f * (float)(lane + 1)); // decay^{lane+1}
        float* H0 = &Hw[(wv * 2 + 0) * 128];
        float* H1 = &Hw[(wv * 2 + 1) * 128];
        H0[lane] = w * v0;  H0[64 + lane] = w * (v0 + f * h063);
        H1[lane] = w * v1;  H1[64 + lane] = w * (v1 + f * h163);
    }
    __syncthreads();

    // ---- per-element descriptors (generic stochastic rounding + clamp) ----
    auto mke = [&](int q, int& o0, int& o1, float& Cw) {   // q in [0, 516)
        int pl = q / 129;
        int d  = q - 129 * pl;
        float dp = delay_param[d];
        float b0 = fmaxf(dp, 0.0f), b1 = fmaxf(-dp, 0.0f);  // relu(cat([dp,-dp]))
        float2 uu = ((const float2*)u)[(p0 + pl) * D_OUTC + d];
        float f0 = floorf(b0), f1 = floorf(b1);
        float r0 = (uu.x < b0 - f0) ? f0 + 1.0f : f0;
        float r1 = (uu.y < b1 - f1) ? f1 + 1.0f : f1;
        int s0 = (int)fminf(r0, (float)caps[pl][0]);
        int s1 = (int)fminf(r1, (float)caps[pl][1]);
        o0 = (pl * 2 + 0) * 128 + 64 - s0;    // gather base; +t stays in [1,127]
        o1 = (pl * 2 + 1) * 128 + 64 - s1;
        Cw = Hw[o0 - 1] + Hw[o1 - 1];         // w*(H0[63-s0]+H1[63-s1])
    };

    int oA0, oA1, oB0, oB1; float CwA, CwB;
    mke(2 * tid,     oA0, oA1, CwA);
    mke(2 * tid + 1, oB0, oB1, CwB);
    const bool xtra = (tid < 2);              // float2 #256,#257 (elements 512..515)
    int oC0 = 0, oC1 = 0, oD0 = 0, oD1 = 0; float CwC = 0.0f, CwDd = 0.0f;
    if (xtra) {
        mke(512 + 2 * tid, oC0, oC1, CwC);
        mke(513 + 2 * tid, oD0, oD1, CwDd);
    }

    float* rp  = out + (size_t)p0 * D_OUTC + 2 * tid;         // 8B-aligned
    float* rpx = out + (size_t)p0 * D_OUTC + 512 + 2 * tid;

    const float K[8] = {1.0f, 0.6065306597126334f, 0.36787944117144233f,
                        0.22313016014842982f, 0.1353352832366127f,
                        0.0820849986238988f, 0.049787068367863944f,
                        0.030197383422318501f};  // decay^j
    float Dg = DECAY;                            // decay^{tg+1}

    for (int tg = 0; tg < T_DIM; tg += 8) {
        float cA = CwA * Dg, cB = CwB * Dg;
        float cC = CwC * Dg, cD = CwDd * Dg;
        #pragma unroll
        for (int j = 0; j < 8; ++j) {
            int t = tg + j;
            v2f v;
            v.x = Hw[oA0 + t] + Hw[oA1 + t] - K[j] * cA;  // 1 gather + 1 broadcast
            v.y = Hw[oB0 + t] + Hw[oB1 + t] - K[j] * cB;
            *(v2f*)(rp + (size_t)t * ROW_STRIDE) = v;     // contiguous 2064B block-span
            if (xtra) {
                v2f vx;
                vx.x = Hw[oC0 + t] + Hw[oC1 + t] - K[j] * cC;
                vx.y = Hw[oD0 + t] + Hw[oD1 + t] - K[j] * cD;
                *(v2f*)(rpx + (size_t)t * ROW_STRIDE) = vx;
            }
        }
        Dg *= 0.01831563888873418f;              // decay^8
    }
}

extern "C" void kernel_launch(void* const* d_in, const int* in_sizes, int n_in,
                              void* d_out, int out_size, void* d_ws, size_t ws_size,
                              hipStream_t stream) {
    const float* input       = (const float*)d_in[0]; // (64,16,256,2)
    const float* delay_param = (const float*)d_in[1]; // (129,1)
    const float* weight      = (const float*)d_in[2]; // scalar
    const float* u           = (const float*)d_in[3]; // (16,256,129,2)
    float* out = (float*)d_out;                       // (64,16,256,129)

    jeffress_kernel<<<NP / PPB, 256, 0, stream>>>(input, delay_param, weight, u, out);
}